// Round 9
// baseline (1353.386 us; speedup 1.0000x reference)
//
#include <hip/hip_runtime.h>
#include <hip/hip_bf16.h>

// DIAGNOSTIC ROUND: R8 kernel (correct, writes d_out) + two 3x-looped
// ablation kernels (no output; opaque-false store keeps work live) to
// decompose the 2470-cyc phase: LDS-read vs staging vs global pacing.

typedef __attribute__((ext_vector_type(4))) float  f32x4;
typedef __attribute__((ext_vector_type(4))) int    i32x4;
typedef __attribute__((ext_vector_type(8))) short  bf16x8;

__device__ __forceinline__ unsigned short f2bf(float f) {
    __hip_bfloat16 h = __float2bfloat16(f);
    return __builtin_bit_cast(unsigned short, h);
}

__device__ __forceinline__ void gload16(const unsigned short* g, unsigned short* l) {
    __builtin_amdgcn_global_load_lds(
        (const __attribute__((address_space(1))) unsigned int*)g,
        (__attribute__((address_space(3))) unsigned int*)l, 16, 0, 0);
}

// ---------------- prepass kernels ----------------

__global__ void convA_kernel(const float* __restrict__ in, unsigned short* __restrict__ o, long n8) {
    long i = (long)blockIdx.x * blockDim.x + threadIdx.x;
    long stride = (long)gridDim.x * blockDim.x;
    const f32x4* in4 = reinterpret_cast<const f32x4*>(in);
    bf16x8* o8 = reinterpret_cast<bf16x8*>(o);
    for (; i < n8; i += stride) {
        f32x4 a = in4[2 * i];
        f32x4 b = in4[2 * i + 1];
        bf16x8 e;
#pragma unroll
        for (int x = 0; x < 4; ++x) {
            e[x]     = (short)f2bf(a[x]);
            e[4 + x] = (short)f2bf(b[x]);
        }
        o8[i] = e;
    }
}

__global__ void dequantW_kernel(const int* __restrict__ Q, const float* __restrict__ lut,
                                unsigned short* __restrict__ Wb, int N, long total) {
    long i = (long)blockIdx.x * blockDim.x + threadIdx.x;
    if (i >= total) return;
    unsigned int v = (unsigned int)Q[i];
    int n = (int)(i % N);
    const float* lp = lut + (long)n * 16;
    bf16x8 w;
#pragma unroll
    for (int p = 0; p < 8; ++p)
        w[p] = (short)f2bf(lp[(v >> (4 * p)) & 15]);
    reinterpret_cast<bf16x8*>(Wb)[i] = w;
}

// ---------------- shared geometry helpers (macro-free common setup) ----------

#define GEOM_SETUP                                                              \
    const int tid  = threadIdx.x;                                               \
    const int lane = tid & 63;                                                  \
    const int wid  = tid >> 6;                                                  \
    const int wr   = wid >> 2;                                                  \
    const int wc   = wid & 3;                                                   \
    const int r15  = lane & 15;                                                 \
    const int hi   = lane >> 4;                                                 \
    const int NBN = N / 256;                                                    \
    int nwg = gridDim.x, orig = blockIdx.x;                                     \
    int wg = ((nwg & 7) == 0) ? (orig & 7) * (nwg >> 3) + (orig >> 3) : orig;   \
    const int m0 = (wg / NBN) * 256, n0 = (wg % NBN) * 256;                     \
    const int NH = K / 32;                                                      \
    const int aoff = (wr * 128 + r15) * 32 + ((hi ^ ((r15 >> 1) & 3)) << 3);    \
    const int boff = hi * 2048 + (wc * 64 + r15) * 8;                           \
    const int am  = tid >> 2, akc = tid & 3;                                    \
    const int akcs = (akc ^ ((am >> 1) & 3)) << 3;                              \
    const unsigned short* baseA0 = Abf + (size_t)(m0 + am) * K + akcs;          \
    const unsigned short* baseA1 = Abf + (size_t)(m0 + am + 128) * K + akcs;    \
    const int bkc = tid >> 8, bn = tid & 255;                                   \
    const unsigned short* baseB0 = Wb + ((size_t)bkc * N + n0 + bn) * 8;        \
    const unsigned short* baseB1 = Wb + ((size_t)(bkc + 2) * N + n0 + bn) * 8;  \
    const size_t bstride = (size_t)32 * N;                                      \
    unsigned short* const dA = sA + wid * 512;                                  \
    unsigned short* const dB = sB + wid * 512;                                  \
    auto stageP1 = [&](int S, int slot) {                                       \
        gload16(baseA0 + S * 32, dA + slot * 8192);                             \
        gload16(baseB0 + S * bstride, dB + slot * 8192);                        \
    };                                                                          \
    auto stageP2 = [&](int S, int slot) {                                       \
        gload16(baseA1 + S * 32, dA + slot * 8192 + 4096);                      \
        gload16(baseB1 + S * bstride, dB + slot * 8192 + 4096);                 \
    };

#define MFMA4(MF, AF) \
    acc[MF][0] = __builtin_amdgcn_mfma_f32_16x16x32_bf16(AF, bv0, acc[MF][0], 0, 0, 0); \
    acc[MF][1] = __builtin_amdgcn_mfma_f32_16x16x32_bf16(AF, bv1, acc[MF][1], 0, 0, 0); \
    acc[MF][2] = __builtin_amdgcn_mfma_f32_16x16x32_bf16(AF, bv2, acc[MF][2], 0, 0, 0); \
    acc[MF][3] = __builtin_amdgcn_mfma_f32_16x16x32_bf16(AF, bv3, acc[MF][3], 0, 0, 0);

// ---------------- FULL kernel (R8, unchanged, writes d_out) ----------------

#define SPH(SLOT, MB, LOADB, STG, WAITSTMT) do {                               \
    const unsigned short* SA_ = sA + (SLOT) * 8192;                            \
    if (LOADB) {                                                               \
        const unsigned short* SB_ = sB + (SLOT) * 8192;                        \
        bv0 = *(const bf16x8*)(SB_ + boff + 0 * 128);                          \
        bv1 = *(const bf16x8*)(SB_ + boff + 1 * 128);                          \
        bv2 = *(const bf16x8*)(SB_ + boff + 2 * 128);                          \
        bv3 = *(const bf16x8*)(SB_ + boff + 3 * 128);                          \
    }                                                                          \
    bf16x8 a0_ = *(const bf16x8*)(SA_ + aoff + ((MB) + 0) * 512);              \
    bf16x8 a1_ = *(const bf16x8*)(SA_ + aoff + ((MB) + 1) * 512);              \
    bf16x8 a2_ = *(const bf16x8*)(SA_ + aoff + ((MB) + 2) * 512);              \
    bf16x8 a3_ = *(const bf16x8*)(SA_ + aoff + ((MB) + 3) * 512);              \
    STG;                                                                       \
    WAITSTMT;                                                                  \
    __builtin_amdgcn_s_barrier();                                              \
    asm volatile("s_waitcnt lgkmcnt(0)" ::: "memory");                         \
    __builtin_amdgcn_sched_barrier(0);                                         \
    __builtin_amdgcn_s_setprio(1);                                             \
    MFMA4((MB) + 0, a0_)                                                       \
    MFMA4((MB) + 1, a1_)                                                       \
    MFMA4((MB) + 2, a2_)                                                       \
    MFMA4((MB) + 3, a3_)                                                       \
    __builtin_amdgcn_s_setprio(0);                                             \
    __builtin_amdgcn_s_barrier();                                              \
} while (0)

#define DPH(S0, S1, H3, H4) do {                                               \
    int S3_ = (H3) >= NH ? (H3) - NH : (H3);                                   \
    int S4_ = (H4) >= NH ? (H4) - NH : (H4);                                   \
    SPH(S0, 0, 1, stageP1(S3_, ((S0) + 3) & 3), );                             \
    SPH(S0, 4, 0, stageP2(S3_, ((S0) + 3) & 3), );                             \
    SPH(S1, 0, 1, stageP1(S4_, (S0)), );                                       \
    SPH(S1, 4, 0, stageP2(S4_, (S0)),                                          \
        asm volatile("s_waitcnt vmcnt(4)" ::: "memory"));                      \
} while (0)

__global__ __launch_bounds__(512, 2)
void gemm8p(const unsigned short* __restrict__ Abf, const unsigned short* __restrict__ Wb,
            float* __restrict__ out, int M, int N, int K) {
    __shared__ __align__(16) unsigned short sA[4 * 8192];
    __shared__ __align__(16) unsigned short sB[4 * 8192];
    GEOM_SETUP

    f32x4 acc[8][4] = {};
    bf16x8 bv0, bv1, bv2, bv3;

    stageP1(0, 0); stageP2(0, 0);
    stageP1(1, 1); stageP2(1, 1);
    stageP1(2, 2); stageP2(2, 2);
    asm volatile("s_waitcnt vmcnt(4)" ::: "memory");
    __builtin_amdgcn_s_barrier();

    for (int h = 0; h < NH; h += 4) {
        DPH(0, 1, h + 3, h + 4);
        DPH(2, 3, h + 5, h + 6);
    }

    asm volatile("s_waitcnt vmcnt(0)" ::: "memory");

#pragma unroll
    for (int mf = 0; mf < 8; ++mf) {
        const int mrow = m0 + wr * 128 + mf * 16 + hi * 4;
#pragma unroll
        for (int nf = 0; nf < 4; ++nf) {
            const int ncol = n0 + wc * 64 + nf * 16 + r15;
            float* po = out + (size_t)mrow * N + ncol;
#pragma unroll
            for (int r = 0; r < 4; ++r) po[(size_t)r * N] = acc[mf][nf][r];
        }
    }
}

#undef DPH
#undef SPH

// ---------------- ABLATION 1: no in-loop staging (ds+MFMA+barriers) --------

#define ASPH(SLOT, MB, LOADB) do {                                             \
    const unsigned short* SA_ = sA + (SLOT) * 8192;                            \
    if (LOADB) {                                                               \
        const unsigned short* SB_ = sB + (SLOT) * 8192;                        \
        bv0 = *(const bf16x8*)(SB_ + boff + 0 * 128);                          \
        bv1 = *(const bf16x8*)(SB_ + boff + 1 * 128);                          \
        bv2 = *(const bf16x8*)(SB_ + boff + 2 * 128);                          \
        bv3 = *(const bf16x8*)(SB_ + boff + 3 * 128);                          \
    }                                                                          \
    bf16x8 a0_ = *(const bf16x8*)(SA_ + aoff + ((MB) + 0) * 512);              \
    bf16x8 a1_ = *(const bf16x8*)(SA_ + aoff + ((MB) + 1) * 512);              \
    bf16x8 a2_ = *(const bf16x8*)(SA_ + aoff + ((MB) + 2) * 512);              \
    bf16x8 a3_ = *(const bf16x8*)(SA_ + aoff + ((MB) + 3) * 512);              \
    __builtin_amdgcn_s_barrier();                                              \
    asm volatile("s_waitcnt lgkmcnt(0)" ::: "memory");                         \
    __builtin_amdgcn_sched_barrier(0);                                         \
    __builtin_amdgcn_s_setprio(1);                                             \
    MFMA4((MB) + 0, a0_)                                                       \
    MFMA4((MB) + 1, a1_)                                                       \
    MFMA4((MB) + 2, a2_)                                                       \
    MFMA4((MB) + 3, a3_)                                                       \
    __builtin_amdgcn_s_setprio(0);                                             \
    __builtin_amdgcn_s_barrier();                                              \
} while (0)

__global__ __launch_bounds__(512, 2)
void abl_nostage(const unsigned short* __restrict__ Abf, const unsigned short* __restrict__ Wb,
                 float* __restrict__ out, int M, int N, int K) {
    __shared__ __align__(16) unsigned short sA[4 * 8192];
    __shared__ __align__(16) unsigned short sB[4 * 8192];
    GEOM_SETUP

    f32x4 acc[8][4] = {};
    bf16x8 bv0, bv1, bv2, bv3;

    stageP1(0, 0); stageP2(0, 0);
    stageP1(1, 1); stageP2(1, 1);
    stageP1(2, 2); stageP2(2, 2);
    asm volatile("s_waitcnt vmcnt(4)" ::: "memory");
    __builtin_amdgcn_s_barrier();

    for (int rep = 0; rep < 3; ++rep) {
        for (int h = 0; h < NH; h += 4) {
            ASPH(0, 0, 1); ASPH(0, 4, 0); ASPH(1, 0, 1); ASPH(1, 4, 0);
            ASPH(2, 0, 1); ASPH(2, 4, 0); ASPH(3, 0, 1); ASPH(3, 4, 0);
        }
    }
    asm volatile("s_waitcnt vmcnt(0)" ::: "memory");

    if (M == 123456789) {  // opaque-false: keeps acc chain live, never stores
        f32x4 s = {};
#pragma unroll
        for (int mf = 0; mf < 8; ++mf)
#pragma unroll
            for (int nf = 0; nf < 4; ++nf) s += acc[mf][nf];
        *(f32x4*)(out + ((size_t)blockIdx.x * 512 + tid) * 4) = s;
    }
}
#undef ASPH

// ---------------- ABLATION 2: no ds_reads (stage+vmcnt+MFMA+barriers) ------

#define NSPH(STG, WAITSTMT, G) do {                                            \
    STG;                                                                       \
    WAITSTMT;                                                                  \
    __builtin_amdgcn_s_barrier();                                              \
    asm volatile("s_waitcnt lgkmcnt(0)" ::: "memory");                         \
    __builtin_amdgcn_sched_barrier(0);                                         \
    __builtin_amdgcn_s_setprio(1);                                             \
    G                                                                          \
    __builtin_amdgcn_s_setprio(0);                                             \
    __builtin_amdgcn_s_barrier();                                              \
} while (0)

#define NG1 MFMA4(0, fa0) MFMA4(1, fa1) MFMA4(2, fa2) MFMA4(3, fa3)
#define NG2 MFMA4(4, fa4) MFMA4(5, fa5) MFMA4(6, fa6) MFMA4(7, fa7)

#define NDPH(S0, S1, H3, H4) do {                                              \
    int S3_ = (H3) >= NH ? (H3) - NH : (H3);                                   \
    int S4_ = (H4) >= NH ? (H4) - NH : (H4);                                   \
    NSPH(stageP1(S3_, ((S0) + 3) & 3), , NG1);                                 \
    NSPH(stageP2(S3_, ((S0) + 3) & 3), , NG2);                                 \
    NSPH(stageP1(S4_, (S0)), , NG1);                                           \
    NSPH(stageP2(S4_, (S0)),                                                   \
         asm volatile("s_waitcnt vmcnt(4)" ::: "memory"), NG2);                \
} while (0)

__global__ __launch_bounds__(512, 2)
void abl_nods(const unsigned short* __restrict__ Abf, const unsigned short* __restrict__ Wb,
              float* __restrict__ out, int M, int N, int K) {
    __shared__ __align__(16) unsigned short sA[4 * 8192];
    __shared__ __align__(16) unsigned short sB[4 * 8192];
    GEOM_SETUP

    f32x4 acc[8][4] = {};

    stageP1(0, 0); stageP2(0, 0);
    stageP1(1, 1); stageP2(1, 1);
    stageP1(2, 2); stageP2(2, 2);
    asm volatile("s_waitcnt vmcnt(4)" ::: "memory");
    __builtin_amdgcn_s_barrier();

    // one-time fragment load (slot 0); frags stay fixed for the whole loop
    bf16x8 bv0 = *(const bf16x8*)(sB + boff + 0 * 128);
    bf16x8 bv1 = *(const bf16x8*)(sB + boff + 1 * 128);
    bf16x8 bv2 = *(const bf16x8*)(sB + boff + 2 * 128);
    bf16x8 bv3 = *(const bf16x8*)(sB + boff + 3 * 128);
    bf16x8 fa0 = *(const bf16x8*)(sA + aoff + 0 * 512);
    bf16x8 fa1 = *(const bf16x8*)(sA + aoff + 1 * 512);
    bf16x8 fa2 = *(const bf16x8*)(sA + aoff + 2 * 512);
    bf16x8 fa3 = *(const bf16x8*)(sA + aoff + 3 * 512);
    bf16x8 fa4 = *(const bf16x8*)(sA + aoff + 4 * 512);
    bf16x8 fa5 = *(const bf16x8*)(sA + aoff + 5 * 512);
    bf16x8 fa6 = *(const bf16x8*)(sA + aoff + 6 * 512);
    bf16x8 fa7 = *(const bf16x8*)(sA + aoff + 7 * 512);

    for (int rep = 0; rep < 3; ++rep) {
        for (int h = 0; h < NH; h += 4) {
            NDPH(0, 1, h + 3, h + 4);
            NDPH(2, 3, h + 5, h + 6);
        }
    }
    asm volatile("s_waitcnt vmcnt(0)" ::: "memory");

    if (M == 123456789) {  // opaque-false: keeps acc chain live, never stores
        f32x4 s = {};
#pragma unroll
        for (int mf = 0; mf < 8; ++mf)
#pragma unroll
            for (int nf = 0; nf < 4; ++nf) s += acc[mf][nf];
        *(f32x4*)(out + ((size_t)blockIdx.x * 512 + tid) * 4) = s;
    }
}
#undef NDPH
#undef NSPH
#undef NG1
#undef NG2

// ---------------- fallback fused kernel (small ws only) ----------------

#define FBM 128
#define FBN 128
#define FBK 64

__device__ __forceinline__ int fswz(int row, int kb) {
    return row * (FBK * 2) + (kb ^ ((row & 7) << 4));
}

__global__ __launch_bounds__(256, 2)
void sqllm_gemm_fused(const float* __restrict__ A, const int* __restrict__ Q,
                      const float* __restrict__ lut, float* __restrict__ out,
                      int M, int N, int K) {
    __shared__ __align__(16) char sA[FBM * FBK * 2];
    __shared__ __align__(16) char sB[FBN * FBK * 2];
    __shared__ float sLut[FBN * 17];

    const int tid  = threadIdx.x;
    const int lane = tid & 63;
    const int wid  = tid >> 6;
    const int wr   = wid >> 1;
    const int wc   = wid & 1;
    const int n0 = blockIdx.x * FBN;
    const int m0 = blockIdx.y * FBM;

    for (int i = tid; i < FBN * 16; i += 256) {
        int n = i >> 4, c = i & 15;
        sLut[n * 17 + c] = lut[(long)(n0 + n) * 16 + c];
    }
    __syncthreads();

    f32x4 acc[4][4] = {};
    const int nK = K / FBK;
    for (int kk = 0; kk < nK; ++kk) {
        {
            const int r = tid >> 1, h = tid & 1;
            const float* ap = A + (long)(m0 + r) * K + kk * FBK + h * 32;
            f32x4 v[8];
#pragma unroll
            for (int j = 0; j < 8; ++j) v[j] = reinterpret_cast<const f32x4*>(ap)[j];
            const int kr = tid >> 5, nq = (tid & 31) << 2;
            const int* qp = Q + (long)(kk * (FBK / 8) + kr) * N + n0 + nq;
            i32x4 q = *reinterpret_cast<const i32x4*>(qp);
#pragma unroll
            for (int j = 0; j < 4; ++j) {
                bf16x8 e;
#pragma unroll
                for (int x = 0; x < 4; ++x) {
                    e[x]     = (short)f2bf(v[2 * j][x]);
                    e[4 + x] = (short)f2bf(v[2 * j + 1][x]);
                }
                *reinterpret_cast<bf16x8*>(sA + fswz(r, h * 64 + j * 16)) = e;
            }
#pragma unroll
            for (int c = 0; c < 4; ++c) {
                const int n = nq + c;
                const float* lp = sLut + n * 17;
                unsigned int qq = (unsigned int)q[c];
                bf16x8 w;
#pragma unroll
                for (int p = 0; p < 8; ++p)
                    w[p] = (short)f2bf(lp[(qq >> (4 * p)) & 15]);
                *reinterpret_cast<bf16x8*>(sB + fswz(n, kr * 16)) = w;
            }
        }
        __syncthreads();
#pragma unroll
        for (int kh = 0; kh < 2; ++kh) {
            const int kb = kh * 64 + (lane >> 4) * 16;
            bf16x8 af[4], bfv[4];
#pragma unroll
            for (int i = 0; i < 4; ++i) {
                af[i]  = *reinterpret_cast<const bf16x8*>(sA + fswz(wr * 64 + i * 16 + (lane & 15), kb));
                bfv[i] = *reinterpret_cast<const bf16x8*>(sB + fswz(wc * 64 + i * 16 + (lane & 15), kb));
            }
#pragma unroll
            for (int i = 0; i < 4; ++i)
#pragma unroll
                for (int j = 0; j < 4; ++j)
                    acc[i][j] = __builtin_amdgcn_mfma_f32_16x16x32_bf16(af[i], bfv[j], acc[i][j], 0, 0, 0);
        }
        __syncthreads();
    }
    const int col = lane & 15;
    const int r4  = (lane >> 4) * 4;
#pragma unroll
    for (int i = 0; i < 4; ++i) {
        const int mrow = m0 + wr * 64 + i * 16 + r4;
#pragma unroll
        for (int j = 0; j < 4; ++j) {
            const int ncol = n0 + wc * 64 + j * 16 + col;
#pragma unroll
            for (int r = 0; r < 4; ++r)
                out[(long)(mrow + r) * N + ncol] = acc[i][j][r];
        }
    }
}

extern "C" void kernel_launch(void* const* d_in, const int* in_sizes, int n_in,
                              void* d_out, int out_size, void* d_ws, size_t ws_size,
                              hipStream_t stream) {
    const float* A   = (const float*)d_in[0];
    const int*   Q   = (const int*)d_in[1];
    const float* lut = (const float*)d_in[2];
    float* out = (float*)d_out;

    const long szA = in_sizes[0], szQ = in_sizes[1], szL = in_sizes[2];
    const int N = (int)(szL / 16);
    const int K = (int)(szQ * 8 / N);
    const int M = (int)(szA / K);

    const size_t needA = (size_t)M * K * 2;
    const size_t needW = (size_t)K * N * 2;

    const bool shape_ok = (M % 256 == 0) && (N % 256 == 0) && (K % 128 == 0);

    if (shape_ok && ws_size >= needA + needW) {
        unsigned short* Abf = (unsigned short*)d_ws;
        unsigned short* Wb  = (unsigned short*)((char*)d_ws + needA);
        const long n8 = (long)M * K / 8;
        convA_kernel<<<2048, 256, 0, stream>>>(A, Abf, n8);
        const long tq = (long)(K / 8) * N;
        dequantW_kernel<<<(int)((tq + 255) / 256), 256, 0, stream>>>(Q, lut, Wb, N, tq);
        dim3 grid((M / 256) * (N / 256));
        gemm8p<<<grid, 512, 0, stream>>>(Abf, Wb, out, M, N, K);
        // diagnostic ablations (no observable writes; M != sentinel)
        abl_nostage<<<grid, 512, 0, stream>>>(Abf, Wb, out, M, N, K);
        abl_nods<<<grid, 512, 0, stream>>>(Abf, Wb, out, M, N, K);
    } else {
        dim3 grid(N / FBN, M / FBM);
        sqllm_gemm_fused<<<grid, 256, 0, stream>>>(A, Q, lut, out, M, N, K);
    }
}

// Round 10
// 293.592 us; speedup vs baseline: 4.6097x; 4.6097x over previous
//
#include <hip/hip_runtime.h>
#include <hip/hip_bf16.h>

// sqllm 4-bit GEMM: out[m,n] = sum_k A[m,k] * lut[n, nibble(qweight[k/8,n], k%8)]
// M=8192, N=4096, K=4096. PRE path: A->bf16, W dequant once, then 256x256 MFMA
// GEMM with cross-phase REGISTER double-buffer, pinned against compiler
// de-pipelining: sched_barrier(0) pins next-half ds_read ISSUE before the
// MFMA burst; a volatile "+v" keep-alive after the burst pins COMPLETION
// after MFMA issue. R9 ablation: MFMA 1172 / ds 716 / stage 672 cyc per half,
// fully serialized -> this phase overlaps ds+stage under MFMA per-wave.

typedef __attribute__((ext_vector_type(4))) float  f32x4;
typedef __attribute__((ext_vector_type(4))) int    i32x4;
typedef __attribute__((ext_vector_type(8))) short  bf16x8;

__device__ __forceinline__ unsigned short f2bf(float f) {
    __hip_bfloat16 h = __float2bfloat16(f);
    return __builtin_bit_cast(unsigned short, h);
}

__device__ __forceinline__ void gload16(const unsigned short* g, unsigned short* l) {
    __builtin_amdgcn_global_load_lds(
        (const __attribute__((address_space(1))) unsigned int*)g,
        (__attribute__((address_space(3))) unsigned int*)l, 16, 0, 0);
}

// ---------------- prepass kernels ----------------

__global__ void convA_kernel(const float* __restrict__ in, unsigned short* __restrict__ o, long n8) {
    long i = (long)blockIdx.x * blockDim.x + threadIdx.x;
    long stride = (long)gridDim.x * blockDim.x;
    const f32x4* in4 = reinterpret_cast<const f32x4*>(in);
    bf16x8* o8 = reinterpret_cast<bf16x8*>(o);
    for (; i < n8; i += stride) {
        f32x4 a = in4[2 * i];
        f32x4 b = in4[2 * i + 1];
        bf16x8 e;
#pragma unroll
        for (int x = 0; x < 4; ++x) {
            e[x]     = (short)f2bf(a[x]);
            e[4 + x] = (short)f2bf(b[x]);
        }
        o8[i] = e;
    }
}

__global__ void dequantW_kernel(const int* __restrict__ Q, const float* __restrict__ lut,
                                unsigned short* __restrict__ Wb, int N, long total) {
    long i = (long)blockIdx.x * blockDim.x + threadIdx.x;
    if (i >= total) return;
    unsigned int v = (unsigned int)Q[i];
    int n = (int)(i % N);
    const float* lp = lut + (long)n * 16;
    bf16x8 w;
#pragma unroll
    for (int p = 0; p < 8; ++p)
        w[p] = (short)f2bf(lp[(v >> (4 * p)) & 15]);
    reinterpret_cast<bf16x8*>(Wb)[i] = w;
}

// ---------------- 256x256 GEMM, pinned reg-pipelined phases ----------------
// 8 waves (2M x 4N), per-wave 128x64 out. LDS: 4-slot ring of 32-k half-tiles.
// Half H -> slot H&3. Phase H: stage half H+3 -> slot (H+3)&3; ds_read half
// H+1's fragments (slot (H+1)&3) into the ALTERNATE reg set; sched_barrier;
// 32 MFMA on CURRENT set; keep-alive pins the new frags; vmcnt(4) (forces
// half H+2, staged one phase ago); barrier. RAW/WAR ledger as R6 (verified).

#define LOADFRAGS(NA, NB, SLOT) do {                                              \
    const unsigned short* SA_ = sA + (SLOT) * 8192;                               \
    const unsigned short* SB_ = sB + (SLOT) * 8192;                               \
    _Pragma("unroll") for (int nf = 0; nf < 4; ++nf)                              \
        NB[nf] = *(const bf16x8*)(SB_ + boff + nf * 128);                         \
    _Pragma("unroll") for (int mf = 0; mf < 8; ++mf)                              \
        NA[mf] = *(const bf16x8*)(SA_ + aoff + mf * 512);                         \
} while (0)

#define MFMABLOCK(CA, CB)                                                         \
    _Pragma("unroll") for (int mf = 0; mf < 8; ++mf)                              \
        _Pragma("unroll") for (int nf = 0; nf < 4; ++nf)                          \
            acc[mf][nf] = __builtin_amdgcn_mfma_f32_16x16x32_bf16(                \
                CA[mf], CB[nf], acc[mf][nf], 0, 0, 0);

// volatile use-site: forces the 12 freshly-read frags to be materialized here
// (lgkm wait lands after the MFMA burst), and forbids sinking past the barrier.
#define KEEPALIVE(NA, NB)                                                         \
    asm volatile("" : "+v"(NA[0]), "+v"(NA[1]), "+v"(NA[2]), "+v"(NA[3]),         \
                      "+v"(NA[4]), "+v"(NA[5]), "+v"(NA[6]), "+v"(NA[7]),         \
                      "+v"(NB[0]), "+v"(NB[1]), "+v"(NB[2]), "+v"(NB[3]))

#define PHASE(U, CA, CB, NA, NB) do {                                             \
    int S = H + (U) + 3; if (S >= NH) S -= NH;                                    \
    stage(S, ((U) + 3) & 3);                                                      \
    LOADFRAGS(NA, NB, ((U) + 1) & 3);                                             \
    __builtin_amdgcn_sched_barrier(0);                                            \
    __builtin_amdgcn_s_setprio(1);                                                \
    MFMABLOCK(CA, CB)                                                             \
    __builtin_amdgcn_s_setprio(0);                                                \
    KEEPALIVE(NA, NB);                                                            \
    asm volatile("s_waitcnt vmcnt(4)" ::: "memory");                              \
    __builtin_amdgcn_s_barrier();                                                 \
} while (0)

__global__ __launch_bounds__(512, 2)
void gemm8p(const unsigned short* __restrict__ Abf, const unsigned short* __restrict__ Wb,
            float* __restrict__ out, int M, int N, int K) {
    __shared__ __align__(16) unsigned short sA[4 * 8192];  // 4 slots x 256m x 32k (kc swizzled)
    __shared__ __align__(16) unsigned short sB[4 * 8192];  // 4 slots x 4kc x 256n x 8

    const int tid  = threadIdx.x;
    const int lane = tid & 63;
    const int wid  = tid >> 6;
    const int wr   = wid >> 2;   // 0..1  (128-row half)
    const int wc   = wid & 3;    // 0..3  (64-col slice)
    const int r15  = lane & 15;
    const int hi   = lane >> 4;

    // XCD-aware bijective swizzle (nwg % 8 == 0 here)
    const int NBN = N / 256;
    int nwg = gridDim.x, orig = blockIdx.x;
    int wg = ((nwg & 7) == 0) ? (orig & 7) * (nwg >> 3) + (orig >> 3) : orig;
    const int m0 = (wg / NBN) * 256, n0 = (wg % NBN) * 256;

    const int NH = K / 32;  // 32-k halves (NH % 4 == 0)

    // per-lane ds_read bases (ushort elements)
    const int aoff = (wr * 128 + r15) * 32 + ((hi ^ ((r15 >> 1) & 3)) << 3);
    const int boff = hi * 2048 + (wc * 64 + r15) * 8;

    // staging bases: 2 A-loads + 2 B-loads per thread per half
    const int am  = tid >> 2, akc = tid & 3;
    const int akcs = (akc ^ ((am >> 1) & 3)) << 3;
    const unsigned short* baseA0 = Abf + (size_t)(m0 + am) * K + akcs;
    const unsigned short* baseA1 = Abf + (size_t)(m0 + am + 128) * K + akcs;
    const int bkc = tid >> 8, bn = tid & 255;
    const unsigned short* baseB0 = Wb + ((size_t)bkc * N + n0 + bn) * 8;
    const unsigned short* baseB1 = Wb + ((size_t)(bkc + 2) * N + n0 + bn) * 8;
    const size_t bstride = (size_t)32 * N;  // per-half advance for B
    unsigned short* const dA = sA + wid * 512;
    unsigned short* const dB = sB + wid * 512;

    auto stage = [&](int S, int slot) {
        gload16(baseA0 + S * 32, dA + slot * 8192);
        gload16(baseB0 + S * bstride, dB + slot * 8192);
        gload16(baseA1 + S * 32, dA + slot * 8192 + 4096);
        gload16(baseB1 + S * bstride, dB + slot * 8192 + 4096);
    };

    f32x4 acc[8][4] = {};
    bf16x8 avA[8], bvA[4], avB[8], bvB[4];

    // prologue: stage halves 0,1,2; vmcnt(4) -> halves 0,1 landed
    stage(0, 0);
    stage(1, 1);
    stage(2, 2);
    asm volatile("s_waitcnt vmcnt(4)" ::: "memory");
    __builtin_amdgcn_s_barrier();
    LOADFRAGS(avA, bvA, 0);  // fragments for half 0

    for (int H = 0; H < NH; H += 4) {
        PHASE(0, avA, bvA, avB, bvB);
        PHASE(1, avB, bvB, avA, bvA);
        PHASE(2, avA, bvA, avB, bvB);
        PHASE(3, avB, bvB, avA, bvA);
    }

    asm volatile("s_waitcnt vmcnt(0)" ::: "memory");  // drain wrap-around prefetches

    // epilogue: C/D layout col=lane&15, row=(lane>>4)*4+reg
#pragma unroll
    for (int mf = 0; mf < 8; ++mf) {
        const int mrow = m0 + wr * 128 + mf * 16 + hi * 4;
#pragma unroll
        for (int nf = 0; nf < 4; ++nf) {
            const int ncol = n0 + wc * 64 + nf * 16 + r15;
            float* po = out + (size_t)mrow * N + ncol;
#pragma unroll
            for (int r = 0; r < 4; ++r) po[(size_t)r * N] = acc[mf][nf][r];
        }
    }
}

#undef PHASE
#undef KEEPALIVE
#undef MFMABLOCK
#undef LOADFRAGS

// ---------------- fallback fused kernel (small ws only) ----------------

#define FBM 128
#define FBN 128
#define FBK 64

__device__ __forceinline__ int fswz(int row, int kb) {
    return row * (FBK * 2) + (kb ^ ((row & 7) << 4));
}

__global__ __launch_bounds__(256, 2)
void sqllm_gemm_fused(const float* __restrict__ A, const int* __restrict__ Q,
                      const float* __restrict__ lut, float* __restrict__ out,
                      int M, int N, int K) {
    __shared__ __align__(16) char sA[FBM * FBK * 2];
    __shared__ __align__(16) char sB[FBN * FBK * 2];
    __shared__ float sLut[FBN * 17];

    const int tid  = threadIdx.x;
    const int lane = tid & 63;
    const int wid  = tid >> 6;
    const int wr   = wid >> 1;
    const int wc   = wid & 1;
    const int n0 = blockIdx.x * FBN;
    const int m0 = blockIdx.y * FBM;

    for (int i = tid; i < FBN * 16; i += 256) {
        int n = i >> 4, c = i & 15;
        sLut[n * 17 + c] = lut[(long)(n0 + n) * 16 + c];
    }
    __syncthreads();

    f32x4 acc[4][4] = {};
    const int nK = K / FBK;
    for (int kk = 0; kk < nK; ++kk) {
        {
            const int r = tid >> 1, h = tid & 1;
            const float* ap = A + (long)(m0 + r) * K + kk * FBK + h * 32;
            f32x4 v[8];
#pragma unroll
            for (int j = 0; j < 8; ++j) v[j] = reinterpret_cast<const f32x4*>(ap)[j];
            const int kr = tid >> 5, nq = (tid & 31) << 2;
            const int* qp = Q + (long)(kk * (FBK / 8) + kr) * N + n0 + nq;
            i32x4 q = *reinterpret_cast<const i32x4*>(qp);
#pragma unroll
            for (int j = 0; j < 4; ++j) {
                bf16x8 e;
#pragma unroll
                for (int x = 0; x < 4; ++x) {
                    e[x]     = (short)f2bf(v[2 * j][x]);
                    e[4 + x] = (short)f2bf(v[2 * j + 1][x]);
                }
                *reinterpret_cast<bf16x8*>(sA + fswz(r, h * 64 + j * 16)) = e;
            }
#pragma unroll
            for (int c = 0; c < 4; ++c) {
                const int n = nq + c;
                const float* lp = sLut + n * 17;
                unsigned int qq = (unsigned int)q[c];
                bf16x8 w;
#pragma unroll
                for (int p = 0; p < 8; ++p)
                    w[p] = (short)f2bf(lp[(qq >> (4 * p)) & 15]);
                *reinterpret_cast<bf16x8*>(sB + fswz(n, kr * 16)) = w;
            }
        }
        __syncthreads();
#pragma unroll
        for (int kh = 0; kh < 2; ++kh) {
            const int kb = kh * 64 + (lane >> 4) * 16;
            bf16x8 af[4], bfv[4];
#pragma unroll
            for (int i = 0; i < 4; ++i) {
                af[i]  = *reinterpret_cast<const bf16x8*>(sA + fswz(wr * 64 + i * 16 + (lane & 15), kb));
                bfv[i] = *reinterpret_cast<const bf16x8*>(sB + fswz(wc * 64 + i * 16 + (lane & 15), kb));
            }
#pragma unroll
            for (int i = 0; i < 4; ++i)
#pragma unroll
                for (int j = 0; j < 4; ++j)
                    acc[i][j] = __builtin_amdgcn_mfma_f32_16x16x32_bf16(af[i], bfv[j], acc[i][j], 0, 0, 0);
        }
        __syncthreads();
    }
    const int col = lane & 15;
    const int r4  = (lane >> 4) * 4;
#pragma unroll
    for (int i = 0; i < 4; ++i) {
        const int mrow = m0 + wr * 64 + i * 16 + r4;
#pragma unroll
        for (int j = 0; j < 4; ++j) {
            const int ncol = n0 + wc * 64 + j * 16 + col;
#pragma unroll
            for (int r = 0; r < 4; ++r)
                out[(long)(mrow + r) * N + ncol] = acc[i][j][r];
        }
    }
}

extern "C" void kernel_launch(void* const* d_in, const int* in_sizes, int n_in,
                              void* d_out, int out_size, void* d_ws, size_t ws_size,
                              hipStream_t stream) {
    const float* A   = (const float*)d_in[0];
    const int*   Q   = (const int*)d_in[1];
    const float* lut = (const float*)d_in[2];
    float* out = (float*)d_out;

    const long szA = in_sizes[0], szQ = in_sizes[1], szL = in_sizes[2];
    const int N = (int)(szL / 16);
    const int K = (int)(szQ * 8 / N);
    const int M = (int)(szA / K);

    const size_t needA = (size_t)M * K * 2;
    const size_t needW = (size_t)K * N * 2;

    const bool shape_ok = (M % 256 == 0) && (N % 256 == 0) && (K % 128 == 0);

    if (shape_ok && ws_size >= needA + needW) {
        unsigned short* Abf = (unsigned short*)d_ws;
        unsigned short* Wb  = (unsigned short*)((char*)d_ws + needA);
        const long n8 = (long)M * K / 8;
        convA_kernel<<<2048, 256, 0, stream>>>(A, Abf, n8);
        const long tq = (long)(K / 8) * N;
        dequantW_kernel<<<(int)((tq + 255) / 256), 256, 0, stream>>>(Q, lut, Wb, N, tq);
        dim3 grid((M / 256) * (N / 256));
        gemm8p<<<grid, 512, 0, stream>>>(Abf, Wb, out, M, N, K);
    } else {
        dim3 grid(N / FBN, M / FBM);
        sqllm_gemm_fused<<<grid, 256, 0, stream>>>(A, Q, lut, out, M, N, K);
    }
}